// Round 21
// baseline (871.093 us; speedup 1.0000x reference)
//
#include <hip/hip_runtime.h>
#include <hip/hip_fp16.h>
#include <math.h>

// Problem constants
#define NS 4096      // N stocks
#define DIM 512      // D
#define NH 8         // heads
#define HD 64        // head dim
#define M2 4098      // N + 2 nodes
#define MPAD 4224    // m padded to multiple of 32
#define KKEEP 2048u  // top-k keep

// Output layout (floats): final_out | raw_scores | gate_mean | attn_mean
#define OUT_F 0
#define OUT_R 2097152          // 4096*512
#define OUT_G 18882560         // + 4096*4098
#define OUT_A 18882561

typedef __attribute__((ext_vector_type(8))) short bf16x8;
typedef __attribute__((ext_vector_type(4))) float f32x4;

__device__ __forceinline__ float sigmoidf_(float x) { return 1.0f / (1.0f + __expf(-x)); }

__device__ __forceinline__ unsigned short btrunc(float f) {   // f32 -> bf16 RNE
  unsigned u = __float_as_uint(f);
  u = u + 0x7FFFu + ((u >> 16) & 1u);
  return (unsigned short)(u >> 16);
}
__device__ __forceinline__ float bton(unsigned short h) {
  return __uint_as_float(((unsigned)h) << 16);
}

// wave suffix-scan over 256 bins (4/lane) and rank pick
__device__ __forceinline__ void scan_pick(unsigned c0, unsigned c1, unsigned c2, unsigned c3,
                                          unsigned k_rem, int lane,
                                          unsigned& bsel_out, unsigned& nxt_out) {
  unsigned run = c0 + c1 + c2 + c3;
  #pragma unroll
  for (int off = 1; off < 64; off <<= 1) {
    unsigned o_ = __shfl_down(run, off, 64);
    if (lane + off < 64) run += o_;
  }
  unsigned s0 = run, s1 = run - c0, s2 = s1 - c1, s3 = s2 - c2, s4 = s3 - c3;
  int which = -1;
  if      (s0 >= k_rem && s1 < k_rem) which = 0;
  else if (s1 >= k_rem && s2 < k_rem) which = 1;
  else if (s2 >= k_rem && s3 < k_rem) which = 2;
  else if (s3 >= k_rem && s4 < k_rem) which = 3;
  unsigned long long bal = __ballot(which >= 0);
  int src = (int)__ffsll(bal) - 1;
  unsigned nxtv = (which == 0) ? s1 : (which == 1) ? s2 : (which == 2) ? s3 : s4;
  unsigned bsel = (unsigned)(4 * lane + (which < 0 ? 0 : which));
  bsel_out = (unsigned)__shfl((int)bsel, src, 64);
  nxt_out  = (unsigned)__shfl((int)nxtv, src, 64);
}

// ---------------- regime_mod = sigmoid([zp,zs] @ Wg.T + bg) ----------------
__global__ __launch_bounds__(256) void regime_kernel(
    const float* __restrict__ zp, const float* __restrict__ zs,
    const float* __restrict__ Wg, const float* __restrict__ bg,
    float* __restrict__ regime) {
  __shared__ float zc[1024];
  int t = threadIdx.x;
  for (int i = t; i < 512; i += 256) { zc[i] = zp[i]; zc[512 + i] = zs[i]; }
  __syncthreads();
  for (int j = t; j < 512; j += 256) {
    const float4* w = (const float4*)(Wg + (size_t)j * 1024);
    float acc = 0.f;
    #pragma unroll 8
    for (int i = 0; i < 256; i++) {
      float4 wv = w[i];
      acc += wv.x * zc[4*i] + wv.y * zc[4*i+1] + wv.z * zc[4*i+2] + wv.w * zc[4*i+3];
    }
    regime[j] = sigmoidf_(acc + bg[j]);
  }
}

// ---------------- generic f32 -> bf16 convert ----------------
__global__ __launch_bounds__(256) void conv_bf(
    const float* __restrict__ src, unsigned short* __restrict__ dst, int n4) {
  int i4 = blockIdx.x * 256 + threadIdx.x;
  if (i4 >= n4) return;
  float4 v = *(const float4*)(src + (size_t)i4 * 4);
  ushort4 o; o.x = btrunc(v.x); o.y = btrunc(v.y); o.z = btrunc(v.z); o.w = btrunc(v.w);
  *(ushort4*)(dst + (size_t)i4 * 4) = o;
}

// ---------------- nodes = concat(zp, zs, sf) in bf16 ----------------
__global__ __launch_bounds__(256) void build_nodes_bf(
    const float* __restrict__ zp, const float* __restrict__ zs,
    const float* __restrict__ sf, unsigned short* __restrict__ nb) {
  int i4 = blockIdx.x * 256 + threadIdx.x;
  if (i4 >= (M2 * DIM) / 4) return;
  int idx = i4 * 4;
  int m = idx >> 9, c = idx & 511;
  const float* src = (m == 0) ? (zp + c) : (m == 1) ? (zs + c)
                               : (sf + (size_t)(m - 2) * 512 + c);
  float4 v = *(const float4*)src;
  ushort4 o; o.x = btrunc(v.x); o.y = btrunc(v.y); o.z = btrunc(v.z); o.w = btrunc(v.w);
  *(ushort4*)(nb + idx) = o;
}

// ---------------- bf16 MFMA GEMM 128x128 (z-batch + per-row scale) ----------------
#define LSTR 40
__global__ __launch_bounds__(256) void gemm_bf16(
    const unsigned short* __restrict__ A, const unsigned short* __restrict__ B,
    const float* __restrict__ bias, const float* __restrict__ cscale,
    const float* __restrict__ rscale,
    float* __restrict__ Cf, unsigned short* __restrict__ Cb,
    int M, int N, int K, int lda, int ldb, int ldc, float scale, int mode,
    size_t sA, size_t sB, size_t sC, size_t sR, int kz, int ksz) {
  __shared__ unsigned short As[128 * LSTR];
  __shared__ unsigned short Bs[128 * LSTR];
  const int z = blockIdx.z;
  const int zh = z / kz, zc = z - zh * kz;
  A += (size_t)zh * sA + (size_t)zc * ksz;
  B += (size_t)zh * sB + (size_t)zc * ksz;
  if (Cf) Cf += (size_t)zh * sC;
  if (Cb) Cb += (size_t)zh * sC;
  if (rscale) rscale += (size_t)zh * sR;
  const int t = threadIdx.x;
  const int w = t >> 6, lane = t & 63;
  const int wr = w >> 1, wc = w & 1;
  const int lr = lane & 15, lg = lane >> 4;
  const int bm = blockIdx.y * 128, bn = blockIdx.x * 128;
  f32x4 acc[4][4] = {};
  for (int k0 = 0; k0 < K; k0 += 32) {
    #pragma unroll
    for (int i = 0; i < 2; i++) {
      int q = t + i * 256;
      int row = q >> 2;
      int ko = (q & 3) * 8;
      bf16x8 av = {};
      int gr = bm + row;
      if (gr < M) av = *(const bf16x8*)(A + (size_t)gr * lda + k0 + ko);
      *(bf16x8*)(As + row * LSTR + ko) = av;
      bf16x8 bv = {};
      int gbr = bn + row;
      if (gbr < N) bv = *(const bf16x8*)(B + (size_t)gbr * ldb + k0 + ko);
      *(bf16x8*)(Bs + row * LSTR + ko) = bv;
    }
    __syncthreads();
    {
      bf16x8 af[4], bfr[4];
      #pragma unroll
      for (int i = 0; i < 4; i++)
        af[i] = *(const bf16x8*)(As + (64 * wr + 16 * i + lr) * LSTR + lg * 8);
      #pragma unroll
      for (int j = 0; j < 4; j++)
        bfr[j] = *(const bf16x8*)(Bs + (64 * wc + 16 * j + lr) * LSTR + lg * 8);
      #pragma unroll
      for (int i = 0; i < 4; i++)
        #pragma unroll
        for (int j = 0; j < 4; j++)
          acc[i][j] = __builtin_amdgcn_mfma_f32_16x16x32_bf16(af[i], bfr[j], acc[i][j], 0, 0, 0);
    }
    __syncthreads();
  }
  #pragma unroll
  for (int i = 0; i < 4; i++) {
    #pragma unroll
    for (int j = 0; j < 4; j++) {
      #pragma unroll
      for (int q = 0; q < 4; q++) {
        int row = bm + 64 * wr + 16 * i + lg * 4 + q;
        int col = bn + 64 * wc + 16 * j + lr;
        if (row < M && col < N) {
          float v = acc[i][j][q] * scale;
          if (bias)   v += bias[col];
          if (cscale) v *= cscale[col];
          if (rscale) v *= rscale[row];
          if (mode == 0)      Cf[(size_t)row * ldc + col] = v;
          else if (mode == 1) Cb[(size_t)row * ldc + col] = btrunc(v);
          else if (mode == 2) Cb[(size_t)col * ldc + row] = btrunc(v);
          else                atomicAdd(&Cf[(size_t)row * ldc + col], v);
        }
      }
    }
  }
}

// ---------------- bf16 MFMA GEMM 128x64 (full-occupancy variant) ----------------
__global__ __launch_bounds__(256) void gemm_n64(
    const unsigned short* __restrict__ A, const unsigned short* __restrict__ B,
    const float* __restrict__ bias, const float* __restrict__ cscale,
    const float* __restrict__ rscale,
    float* __restrict__ Cf, unsigned short* __restrict__ Cb,
    int M, int N, int K, int lda, int ldb, int ldc, float scale, int mode,
    size_t sA, size_t sB, size_t sC, size_t sR, int kz, int ksz) {
  __shared__ unsigned short As[128 * LSTR];
  __shared__ unsigned short Bs[64 * LSTR];
  const int z = blockIdx.z;
  const int zh = z / kz, zc = z - zh * kz;
  A += (size_t)zh * sA + (size_t)zc * ksz;
  B += (size_t)zh * sB + (size_t)zc * ksz;
  if (Cf) Cf += (size_t)zh * sC;
  if (Cb) Cb += (size_t)zh * sC;
  if (rscale) rscale += (size_t)zh * sR;
  const int t = threadIdx.x;
  const int w = t >> 6, lane = t & 63;
  const int lr = lane & 15, lg = lane >> 4;
  const int bm = blockIdx.y * 128, bn = blockIdx.x * 64;
  f32x4 acc[2][4] = {};
  for (int k0 = 0; k0 < K; k0 += 32) {
    {
      #pragma unroll
      for (int i = 0; i < 2; i++) {
        int q = t + i * 256;
        int row = q >> 2;
        int ko = (q & 3) * 8;
        bf16x8 av = {};
        int gr = bm + row;
        if (gr < M) av = *(const bf16x8*)(A + (size_t)gr * lda + k0 + ko);
        *(bf16x8*)(As + row * LSTR + ko) = av;
      }
      int row = t >> 2;
      int ko = (t & 3) * 8;
      bf16x8 bv = {};
      int gbr = bn + row;
      if (gbr < N) bv = *(const bf16x8*)(B + (size_t)gbr * ldb + k0 + ko);
      *(bf16x8*)(Bs + row * LSTR + ko) = bv;
    }
    __syncthreads();
    {
      bf16x8 af[2], bfr[4];
      #pragma unroll
      for (int i = 0; i < 2; i++)
        af[i] = *(const bf16x8*)(As + (32 * w + 16 * i + lr) * LSTR + lg * 8);
      #pragma unroll
      for (int j = 0; j < 4; j++)
        bfr[j] = *(const bf16x8*)(Bs + (16 * j + lr) * LSTR + lg * 8);
      #pragma unroll
      for (int i = 0; i < 2; i++)
        #pragma unroll
        for (int j = 0; j < 4; j++)
          acc[i][j] = __builtin_amdgcn_mfma_f32_16x16x32_bf16(af[i], bfr[j], acc[i][j], 0, 0, 0);
    }
    __syncthreads();
  }
  #pragma unroll
  for (int i = 0; i < 2; i++) {
    #pragma unroll
    for (int j = 0; j < 4; j++) {
      #pragma unroll
      for (int q = 0; q < 4; q++) {
        int row = bm + 32 * w + 16 * i + lg * 4 + q;
        int col = bn + 16 * j + lr;
        if (row < M && col < N) {
          float v = acc[i][j][q] * scale;
          if (bias)   v += bias[col];
          if (cscale) v *= cscale[col];
          if (rscale) v *= rscale[row];
          if (mode == 0)      Cf[(size_t)row * ldc + col] = v;
          else if (mode == 1) Cb[(size_t)row * ldc + col] = btrunc(v);
          else if (mode == 2) Cb[(size_t)col * ldc + row] = btrunc(v);
          else                atomicAdd(&Cf[(size_t)row * ldc + col], v);
        }
      }
    }
  }
}

// ---------------- select + exp + raw_scores + attn_mean (block per n, 8 waves = 8 heads) ----------------
// v5 = v4 + per-thread 6-slot bin accumulator in s1 (scores concentrate in ~6-10
// hi-byte bins -> 66 same-bin LDS atomics/thread collapse to <=6 flush atomics).
#define ACC6(binv)                                            \
  {  unsigned _b = (binv);                                    \
     if      (_b == b0) n0++;                                 \
     else if (_b == b1) n1++;                                 \
     else if (_b == b2) n2++;                                 \
     else if (_b == b3) n3++;                                 \
     else if (_b == b4) n4++;                                 \
     else if (_b == b5) n5++;                                 \
     else if (b0 == 0x100u) { b0 = _b; n0 = 1; }              \
     else if (b1 == 0x100u) { b1 = _b; n1 = 1; }              \
     else if (b2 == 0x100u) { b2 = _b; n2 = 1; }              \
     else if (b3 == 0x100u) { b3 = _b; n3 = 1; }              \
     else if (b4 == 0x100u) { b4 = _b; n4 = 1; }              \
     else if (b5 == 0x100u) { b5 = _b; n5 = 1; }              \
     else atomicAdd(&hw[_b], 1u);  }
#define SSMEM (8 * MPAD * 2 + 8 * 256 * 4 + 32 + 32)   // 75840 -> 2 blocks/CU
__global__ __launch_bounds__(512) void select_softmax(
    unsigned short* __restrict__ S, float* __restrict__ Zg,
    float* __restrict__ outA, float* __restrict__ outR) {
  extern __shared__ char sm[];
  unsigned short* keys = (unsigned short*)sm;              // [8][MPAD]
  unsigned* hist = (unsigned*)(sm + 8 * MPAD * 2);         // [8][256]
  float* Zs = (float*)(sm + 8 * MPAD * 2 + 8 * 256 * 4);   // [8]
  unsigned short* anchk = (unsigned short*)(sm + 8 * MPAD * 2 + 8 * 256 * 4 + 32); // [8][2]
  const int w = threadIdx.x >> 6, lane = threadIdx.x & 63;
  const int n = blockIdx.x;
  const size_t row = (size_t)w * 4096 + n;                 // head = w
  unsigned short* kr = keys + w * MPAD;
  unsigned* hw = hist + w * 256;
  unsigned short* g = S + row * MPAD;
  unsigned a0k = 0, a1k = 0;

  // s1: global read -> keys -> LDS + 6-slot local hi-byte hist + max
  hw[lane] = 0u; hw[lane + 64] = 0u; hw[lane + 128] = 0u; hw[lane + 192] = 0u;
  unsigned maxkey = 0;
  unsigned b0 = 0x100u, b1 = 0x100u, b2 = 0x100u, b3 = 0x100u, b4 = 0x100u, b5 = 0x100u;
  unsigned n0 = 0, n1 = 0, n2 = 0, n3 = 0, n4 = 0, n5 = 0;
  #pragma unroll
  for (int c = 0; c < 9; ++c) {
    if (c < 8 || lane < 16) {
      uint4 v = *(const uint4*)(g + c * 512 + lane * 8);
      unsigned* pv = (unsigned*)&v;
      int mb = c * 512 + lane * 8;
      #pragma unroll
      for (int p2 = 0; p2 < 4; ++p2) {
        unsigned pk = pv[p2], outw = 0;
        #pragma unroll
        for (int e = 0; e < 2; ++e) {
          int m = mb + 2 * p2 + e;
          unsigned u = (e == 0) ? (pk & 0xFFFFu) : (pk >> 16);
          unsigned key = u ^ ((u & 0x8000u) ? 0xFFFFu : 0x8000u);
          if (m < 2) { if (m == 0) a0k = key; else a1k = key; key = 0u; }
          else if (m >= M2) key = 0u;
          outw |= key << (16 * e);
          ACC6(key >> 8);
          if (key > maxkey) maxkey = key;
        }
        *(unsigned*)(kr + mb + 2 * p2) = outw;
      }
    }
  }
  // flush local slots
  if (b0 != 0x100u) atomicAdd(&hw[b0], n0);
  if (b1 != 0x100u) atomicAdd(&hw[b1], n1);
  if (b2 != 0x100u) atomicAdd(&hw[b2], n2);
  if (b3 != 0x100u) atomicAdd(&hw[b3], n3);
  if (b4 != 0x100u) atomicAdd(&hw[b4], n4);
  if (b5 != 0x100u) atomicAdd(&hw[b5], n5);
  if (lane == 0) { anchk[w * 2] = (unsigned short)a0k; anchk[w * 2 + 1] = (unsigned short)a1k; }
  if (a0k > maxkey) maxkey = a0k;   // nonzero only on lane 0
  if (a1k > maxkey) maxkey = a1k;
  #pragma unroll
  for (int off = 32; off > 0; off >>= 1) {
    unsigned o_ = (unsigned)__shfl_xor((int)maxkey, off, 64);
    if (o_ > maxkey) maxkey = o_;
  }
  float lmax = bton((unsigned short)(maxkey ^ ((maxkey & 0x8000u) ? 0x8000u : 0xFFFFu)));

  unsigned tb, k_rem = KKEEP;
  {
    unsigned c0 = hw[4*lane], c1 = hw[4*lane+1], c2 = hw[4*lane+2], c3 = hw[4*lane+3];
    unsigned nxtv;
    scan_pick(c0, c1, c2, c3, k_rem, lane, tb, nxtv);
    k_rem -= nxtv;
  }

  // s2: boundary-bin low-byte histogram (LDS keys)
  hw[lane] = 0u; hw[lane + 64] = 0u; hw[lane + 128] = 0u; hw[lane + 192] = 0u;
  #pragma unroll
  for (int c = 0; c < 9; ++c) {
    if (c < 8 || lane < 16) {
      uint4 v = *(const uint4*)(kr + c * 512 + lane * 8);
      const unsigned* pv = (const unsigned*)&v;
      #pragma unroll
      for (int p2 = 0; p2 < 4; ++p2) {
        unsigned lo = pv[p2] & 0xFFFFu, hi = pv[p2] >> 16;
        if ((lo >> 8) == tb) atomicAdd(&hw[lo & 255u], 1u);
        if ((hi >> 8) == tb) atomicAdd(&hw[hi & 255u], 1u);
      }
    }
  }
  unsigned thrkey;
  {
    unsigned c0 = hw[4*lane], c1 = hw[4*lane+1], c2 = hw[4*lane+2], c3 = hw[4*lane+3];
    unsigned bsel, nxtv;
    scan_pick(c0, c1, c2, c3, k_rem, lane, bsel, nxtv);
    thrkey = (tb << 8) | bsel;
  }
  __syncthreads();   // all waves' keys + anchk staged

  // raw pass: reconstruct S from keys (all heads) -> outR
  for (int m = threadIdx.x; m < M2; m += 512) {
    float s = 0.f;
    #pragma unroll
    for (int h = 0; h < 8; ++h) {
      unsigned key = (m < 2) ? (unsigned)anchk[h * 2 + m] : (unsigned)keys[h * MPAD + m];
      unsigned short us = (unsigned short)(key ^ ((key & 0x8000u) ? 0x8000u : 0xFFFFu));
      s += bton(us);
    }
    outR[(size_t)n * M2 + m] = s * 0.125f;
  }
  __syncthreads();   // raw reads done before e overwrite

  // s3: exp -> unnormalized e (bf16) to LDS + global; lsum of rounded e
  float lsum = 0.f;
  #pragma unroll
  for (int c = 0; c < 9; ++c) {
    if (c < 8 || lane < 16) {
      uint4 v = *(const uint4*)(kr + c * 512 + lane * 8);
      unsigned* pv = (unsigned*)&v;
      #pragma unroll
      for (int p2 = 0; p2 < 4; ++p2) {
        unsigned pk = pv[p2], outw = 0;
        bool anc = (c == 0 && lane == 0 && p2 == 0);
        if (anc) pk = a0k | (a1k << 16);
        #pragma unroll
        for (int e = 0; e < 2; ++e) {
          unsigned key = (e == 0) ? (pk & 0xFFFFu) : (pk >> 16);
          bool kept = anc || (key >= thrkey);
          unsigned short us = (unsigned short)(key ^ ((key & 0x8000u) ? 0x8000u : 0xFFFFu));
          float ev = kept ? __expf(bton(us) - lmax) : 0.f;
          unsigned short eb = btrunc(ev);
          lsum += bton(eb);
          outw |= ((unsigned)eb) << (16 * e);
        }
        pv[p2] = outw;
      }
      *(uint4*)(kr + c * 512 + lane * 8) = v;   // e into LDS for attn_mean
      *(uint4*)(g + c * 512 + lane * 8) = v;    // e to global for PV
    }
  }
  #pragma unroll
  for (int off = 32; off > 0; off >>= 1) lsum += __shfl_xor(lsum, off, 64);
  float invZ = 1.0f / lsum;
  if (lane == 0) { Zg[row] = invZ; Zs[w] = invZ; }
  __syncthreads();   // e + Zs visible to whole block

  // am pass: attn_mean[n][m] = (1/8) sum_h e[h][m] * invZ[h]
  for (int m = threadIdx.x; m < M2; m += 512) {
    float s = 0.f;
    #pragma unroll
    for (int h = 0; h < 8; ++h)
      s += bton(keys[h * MPAD + m]) * Zs[h];
    outA[(size_t)n * M2 + m] = s * 0.125f;
  }
}

// ================= FALLBACK PATH (round-14 fused kernel) =================
#define SROWB 8464
#define QOFF  (16 * SROWB)
#define HOFF  (QOFF + 16 * 72 * 2)
#define AOFF  (HOFF + 16 * 256 * 4)
#define SMEMSZ (AOFF + 64)

__global__ __launch_bounds__(1024) void fused_attn(
    const unsigned short* __restrict__ Qbf, const unsigned short* __restrict__ Kbf,
    const unsigned short* __restrict__ Vt, unsigned short* __restrict__ aobf,
    float* __restrict__ attn_mean_out) {
  extern __shared__ char dsm[];
  unsigned short* qt = (unsigned short*)(dsm + QOFF);
  unsigned* hist = (unsigned*)(dsm + HOFF);
  unsigned short* anchk = (unsigned short*)(dsm + AOFF);
  const int n0 = blockIdx.x * 16;
  const int t = threadIdx.x;
  const int w = t >> 6, lane = t & 63;
  const int lr = lane & 15, lg = lane >> 4;
  unsigned* hw = hist + w * 256;
  const int r = w;
  const unsigned swz = (unsigned)((r & 7) << 4);

  for (int h = 0; h < NH; ++h) {
    qt[(t >> 6) * 72 + (t & 63)] = Qbf[(size_t)(n0 + (t >> 6)) * DIM + h * HD + (t & 63)];
    __syncthreads();
    {
      bf16x8 a0 = *(const bf16x8*)(qt + lr * 72 + lg * 8);
      bf16x8 a1 = *(const bf16x8*)(qt + lr * 72 + 32 + lg * 8);
      #pragma unroll
      for (int f = 0; f < 17; ++f) {
        if (f < 16 || w < 8) {
          int m0 = (w + 16 * f) * 16;
          const unsigned short* kp = Kbf + (size_t)(m0 + lr) * DIM + h * HD + lg * 8;
          bf16x8 b0 = *(const bf16x8*)(kp);
          bf16x8 b1 = *(const bf16x8*)(kp + 32);
          f32x4 c = {0.f, 0.f, 0.f, 0.f};
          c = __builtin_amdgcn_mfma_f32_16x16x32_bf16(a0, b0, c, 0, 0, 0);
          c = __builtin_amdgcn_mfma_f32_16x16x32_bf16(a1, b1, c, 0, 0, 0);
          int m = m0 + lr;
          #pragma unroll
          for (int q = 0; q < 4; ++q) {
            int rr = lg * 4 + q;
            unsigned short us = btrunc(c[q] * 0.125f);
            unsigned key = (unsigned)us ^ ((us & 0x8000u) ? 0xFFFFu : 0x8000u);
            unsigned short stor = (m >= M2 || m < 2) ? (unsigned short)0 : (unsigned short)key;
            *(unsigned short*)(dsm + rr * SROWB + ((2 * m) ^ ((rr & 7) << 4))) = stor;
            if (m < 2) anchk[rr * 2 + m] = (unsigned short)key;
          }
        }
      }
    }
    __syncthreads();

    float invZ;
    {
      unsigned maxkey = 0;
      hw[lane] = 0u; hw[lane + 64] = 0u; hw[lane + 128] = 0u; hw[lane + 192] = 0u;
      #pragma unroll
      for (int c = 0; c < 9; ++c) {
        if (c < 8 || lane < 16) {
          uint4 pk4 = *(const uint4*)(dsm + r * SROWB + (((unsigned)(c * 1024 + lane * 16)) ^ swz));
          const unsigned* pw = (const unsigned*)&pk4;
          #pragma unroll
          for (int p2 = 0; p2 < 4; ++p2) {
            unsigned pk = pw[p2];
            unsigned lo = pk & 0xFFFFu, hi = pk >> 16;
            atomicAdd(&hw[lo >> 8], 1u);
            atomicAdd(&hw[hi >> 8], 1u);
            if (lo > maxkey) maxkey = lo;
            if (hi > maxkey) maxkey = hi;
          }
        }
      }
      #pragma unroll
      for (int off = 32; off > 0; off >>= 1) {
        unsigned o_ = (unsigned)__shfl_xor((int)maxkey, off, 64);
        if (o_ > maxkey) maxkey = o_;
      }
      {
        unsigned a0 = anchk[2 * r], a1 = anchk[2 * r + 1];
        if (a0 > maxkey) maxkey = a0;
        if (a1 > maxkey) maxkey = a1;
      }
      float lmax = bton((unsigned short)(maxkey ^ ((maxkey & 0x8000u) ? 0x8000u : 0xFFFFu)));

      unsigned tb, k_rem = KKEEP;
      {
        unsigned c0 = hw[4*lane], c1 = hw[4*lane+1], c2 = hw[4*lane+2], c3 = hw[4*lane+3];
        unsigned nxtv;
        scan_pick(c0, c1, c2, c3, k_rem, lane, tb, nxtv);
        k_rem -= nxtv;
      }
      hw[lane] = 0u; hw[lane + 64] = 0u; hw[lane + 128] = 0u; hw[lane + 192] = 0u;
      #pragma unroll
      for (int c = 0; c < 9; ++c) {
        if (c < 8 || lane < 16) {
          uint4 pk4 = *(const uint4*)(dsm + r * SROWB + (((unsigned)(c * 1024 + lane * 16)) ^ swz));
          const unsigned* pw = (const unsigned*)&pk4;
          #pragma unroll
          for (int p2 = 0; p2 < 4; ++p2) {
            unsigned pk = pw[p2];
            unsigned lo = pk & 0xFFFFu, hi = pk >> 16;
            if ((lo >> 8) == tb) atomicAdd(&hw[lo & 255u], 1u);
            if ((hi >> 8) == tb) atomicAdd(&hw[hi & 255u], 1u);
          }
        }
      }
      unsigned thrkey;
      {
        unsigned c0 = hw[4*lane], c1 = hw[4*lane+1], c2 = hw[4*lane+2], c3 = hw[4*lane+3];
        unsigned bsel, nxtv;
        scan_pick(c0, c1, c2, c3, k_rem, lane, bsel, nxtv);
        thrkey = (tb << 8) | bsel;
      }

      float lsum = 0.f;
      #pragma unroll
      for (int c = 0; c < 9; ++c) {
        if (c < 8 || lane < 16) {
          char* ap = dsm + r * SROWB + (((unsigned)(c * 1024 + lane * 16)) ^ swz);
          uint4 pk4 = *(const uint4*)ap;
          unsigned* pw = (unsigned*)&pk4;
          #pragma unroll
          for (int p2 = 0; p2 < 4; ++p2) {
            unsigned pk = pw[p2];
            bool anc = (c == 0 && lane == 0 && p2 == 0);
            if (anc) pk = (unsigned)anchk[2 * r] | ((unsigned)anchk[2 * r + 1] << 16);
            unsigned outw = 0;
            #pragma unroll
            for (int e = 0; e < 2; ++e) {
              unsigned key = (e == 0) ? (pk & 0xFFFFu) : (pk >> 16);
              bool kept = anc || (key >= thrkey);
              unsigned short us = (unsigned short)(key ^ ((key & 0x8000u) ? 0x8000u : 0xFFFFu));
              float evf = kept ? __expf(bton(us) - lmax) : 0.f;
              unsigned short eb = btrunc(evf);
              lsum += bton(eb);
              outw |= ((unsigned)eb) << (16 * e);
            }
            pw[p2] = outw;
          }
          *(uint4*)ap = pk4;
        }
      }
      #pragma unroll
      for (int off = 32; off > 0; off >>= 1) lsum += __shfl_xor(lsum, off, 64);
      invZ = 1.0f / lsum;
      for (int c = 0; c < 9; ++c) {
        if (c < 8 || lane < 16) {
          const char* ap = dsm + r * SROWB + (((unsigned)(c * 1024 + lane * 16)) ^ swz);
          uint4 e4 = *(const uint4*)ap;
          const unsigned* pw = (const unsigned*)&e4;
          int bm = c * 512 + lane * 8;
          float* base = attn_mean_out + (size_t)(n0 + r) * M2 + bm;
          #pragma unroll
          for (int p2 = 0; p2 < 4; ++p2) {
            float v0 = bton((unsigned short)(pw[p2] & 0xFFFFu)) * invZ * 0.125f;
            float v1 = bton((unsigned short)(pw[p2] >> 16)) * invZ * 0.125f;
            int m = bm + 2 * p2;
            if (m < M2)     { if (h == 0) base[2*p2] = v0;   else base[2*p2] += v0; }
            if (m + 1 < M2) { if (h == 0) base[2*p2+1] = v1; else base[2*p2+1] += v1; }
          }
        }
      }
    }
    __syncthreads();

    {
      f32x4 o0 = {0.f,0.f,0.f,0.f}, o1 = o0, o2 = o0, o3 = o0;
      const unsigned short* Vb = Vt + (size_t)(h * HD) * MPAD;
      #pragma unroll
      for (int ks = 0; ks < 9; ++ks) {
        if (ks < 8 || w < 4) {
          int kk = (w + 16 * ks) * 32 + lg * 8;
          bf16x8 a = *(const bf16x8*)(dsm + lr * SROWB + ((2 * kk) ^ ((lr & 7) << 4)));
          {
            bf16x8 b0 = *(const bf16x8*)(Vb + (size_t)(lr) * MPAD + kk);
            bf16x8 b1 = *(const bf16x8*)(Vb + (size_t)(16 + lr) * MPAD + kk);
            o0 = __builtin_amdgcn_mfma_f32_16x16x32_bf16(a, b0, o0, 0, 0, 0);
            o1 = __builtin_amdgcn_mfma_f32_16x16x32_bf16(a, b1, o1, 0, 0, 0);
          }
          {
            bf16x8 b2 = *(const bf16x8*)(Vb + (size_t)(32 + lr) * MPAD + kk);
            bf16x8 b3 = *(const bf16x8*)(Vb + (size_t)(48 + lr) * MPAD + kk);
            o2 = __builtin_amdgcn_mfma_f32_16x16x32_bf16(a, b2, o2, 0, 0, 0);
            o3 = __builtin_amdgcn_mfma_f32_16x16x32_bf16(a, b3, o3, 0, 0, 0);
          }
        }
      }
      __syncthreads();
      float* part = (float*)dsm;
      #pragma unroll
      for (int q = 0; q < 4; q++) {
        int row = lg * 4 + q;
        part[w * 1024 + row * 64 +      lr] = o0[q];
        part[w * 1024 + row * 64 + 16 + lr] = o1[q];
        part[w * 1024 + row * 64 + 32 + lr] = o2[q];
        part[w * 1024 + row * 64 + 48 + lr] = o3[q];
      }
      __syncthreads();
      {
        float s = 0.f;
        #pragma unroll
        for (int ww = 0; ww < 16; ++ww) s += part[ww * 1024 + t];
        aobf[(size_t)(n0 + (t >> 6)) * DIM + h * HD + (t & 63)] = btrunc(s * invZ);
      }
    }
  }
}

// ---------------- concat(sfbf, bf16(pj)) ----------------
__global__ __launch_bounds__(256) void cat_bf(
    const unsigned short* __restrict__ sfbf, const float* __restrict__ pj,
    unsigned short* __restrict__ cat) {
  int i4 = blockIdx.x * 256 + threadIdx.x;
  if (i4 >= (4096 * 1024) / 4) return;
  int idx = i4 * 4;
  int n = idx >> 10, c = idx & 1023;
  if (c < 512) {
    *(ushort4*)(cat + idx) = *(const ushort4*)(sfbf + (size_t)n * 512 + c);
  } else {
    float4 v = *(const float4*)(pj + (size_t)n * 512 + (c - 512));
    ushort4 o; o.x = btrunc(v.x); o.y = btrunc(v.y); o.z = btrunc(v.z); o.w = btrunc(v.w);
    *(ushort4*)(cat + idx) = o;
  }
}

// ---------------- gate, residual, RMSNorm, gate partial sums ----------------
__global__ __launch_bounds__(256) void final_kernel(
    const float* __restrict__ sf, const float* __restrict__ pj,
    const float* __restrict__ gl, const float* __restrict__ norm_w,
    float* __restrict__ outf, float* __restrict__ gpart) {
  int n = blockIdx.x, t = threadIdx.x;
  __shared__ float red[256];
  size_t base = (size_t)n * 512;
  float g0 = sigmoidf_(gl[base + t]);
  float g1 = sigmoidf_(gl[base + 256 + t]);
  float x0 = sf[base + t], x1 = sf[base + 256 + t];
  float p0 = pj[base + t], p1 = pj[base + 256 + t];
  float gr0 = x0 + g0 * p0, gr1 = x1 + g1 * p1;

  red[t] = g0 + g1;
  __syncthreads();
  for (int off = 128; off > 0; off >>= 1) {
    if (t < off) red[t] += red[t + off];
    __syncthreads();
  }
  if (t == 0) gpart[n] = red[0];
  __syncthreads();

  red[t] = gr0 * gr0 + gr1 * gr1;
  __syncthreads();
  for (int off = 128; off > 0; off >>= 1) {
    if (t < off) red[t] += red[t + off];
    __syncthreads();
  }
  float rms = rsqrtf(red[0] * (1.0f / 512.0f) + 1e-6f);
  outf[base + t] = gr0 * rms * norm_w[t];
  outf[base + 256 + t] = gr1 * rms * norm_w[256 + t];
}

__global__ __launch_bounds__(256) void gate_reduce(
    const float* __restrict__ gpart, float* __restrict__ out_scalar) {
  __shared__ float red[256];
  int t = threadIdx.x;
  float s = 0.f;
  for (int i = t; i < 4096; i += 256) s += gpart[i];
  red[t] = s;
  __syncthreads();
  for (int off = 128; off > 0; off >>= 1) {
    if (t < off) red[t] += red[t + off];
    __syncthreads();
  }
  if (t == 0) out_scalar[0] = red[0] * (1.0f / (4096.0f * 512.0f));
}

extern "C" void kernel_launch(void* const* d_in, const int* in_sizes, int n_in,
                              void* d_out, int out_size, void* d_ws, size_t ws_size,
                              hipStream_t stream) {
  const float* sf  = (const float*)d_in[0];
  const float* zp  = (const float*)d_in[1];
  const float* zs  = (const float*)d_in[2];
  const float* Wq  = (const float*)d_in[3];
  const float* Wk  = (const float*)d_in[4];
  const float* Wv  = (const float*)d_in[5];
  const float* Wg  = (const float*)d_in[6];
  const float* bg  = (const float*)d_in[7];
  const float* Wag = (const float*)d_in[8];
  const float* bag = (const float*)d_in[9];
  const float* nw  = (const float*)d_in[10];
  const float* Wo  = (const float*)d_in[11];
  const float* bo  = (const float*)d_in[12];

  float* out  = (float*)d_out;
  float* outF = out + OUT_F;
  float* outR = out + OUT_R;
  float* outG = out + OUT_G;
  float* outA = out + OUT_A;

  // workspace layout (bytes)
  char* W = (char*)d_ws;
  float*          regime  = (float*)(W + 0);                 // 2048
  float*          gpart   = (float*)(W + 2048);              // 16384
  unsigned short* sfbf    = (unsigned short*)(W + 18432);    // 4,194,304
  unsigned short* nodesbf = (unsigned short*)(W + 4212736);  // 4,196,352
  unsigned short* Qbf     = (unsigned short*)(W + 8409088);  // 4,194,304
  unsigned short* Kbf     = (unsigned short*)(W + 12603392); // 4,325,376
  unsigned short* Vt      = (unsigned short*)(W + 16928768); // 4,325,376 (512 x 4224)
  unsigned short* aobf    = (unsigned short*)(W + 21254144); // 4,194,304
  unsigned short* catbf   = (unsigned short*)(W + 25448448); // 8,388,608
  unsigned short* Wqbf    = (unsigned short*)(W + 33837056); // 524,288
  unsigned short* Wkbf    = (unsigned short*)(W + 34361344); // 524,288
  unsigned short* Wvbf    = (unsigned short*)(W + 34885632); // 524,288
  unsigned short* Wobf    = (unsigned short*)(W + 35409920); // 524,288
  unsigned short* Wagbf   = (unsigned short*)(W + 35934208); // 1,048,576
  float*          pj      = (float*)(W + 36982784);          // 8,388,608 -> 45,371,392
  float*          gl      = (float*)(W + 4212736);           // alias (dead by then)
  unsigned short* Splane  = (unsigned short*)(W + 45371392); // 276,824,064 -> 322,195,456
  float*          Zg      = (float*)(W + 322195456);         // 131,072 -> 322,326,528
  float*          aopf    = (float*)(W + 322326528);         // 8,388,608 -> 330,715,136
  const size_t need_s = 330715136ull;
  const int use_s = (ws_size >= need_s) ? 1 : 0;

  hipFuncSetAttribute((const void*)fused_attn,
                      hipFuncAttributeMaxDynamicSharedMemorySize, SMEMSZ);
  hipFuncSetAttribute((const void*)select_softmax,
                      hipFuncAttributeMaxDynamicSharedMemorySize, SSMEM);

  // --- small prep ---
  regime_kernel<<<1, 256, 0, stream>>>(zp, zs, Wg, bg, regime);
  conv_bf<<<2048, 256, 0, stream>>>(sf, sfbf, 524288);
  build_nodes_bf<<<2049, 256, 0, stream>>>(zp, zs, sf, nodesbf);
  conv_bf<<<256, 256, 0, stream>>>(Wq, Wqbf, 65536);
  conv_bf<<<256, 256, 0, stream>>>(Wk, Wkbf, 65536);
  conv_bf<<<256, 256, 0, stream>>>(Wv, Wvbf, 65536);
  conv_bf<<<256, 256, 0, stream>>>(Wo, Wobf, 65536);
  conv_bf<<<512, 256, 0, stream>>>(Wag, Wagbf, 131072);
  hipMemsetAsync(Kbf, 0, 4325376, stream);
  hipMemsetAsync(Vt, 0, 4325376, stream);

  // --- projections (bf16 MFMA, 128x64 tiles) ---
  gemm_n64<<<dim3(8, 32, 1), 256, 0, stream>>>(sfbf, Wqbf, nullptr, regime, nullptr, nullptr, Qbf,
                                               4096, 512, 512, 512, 512, 512, 1.0f, 1, 0, 0, 0, 0, 1, 0);
  gemm_n64<<<dim3(8, 33, 1), 256, 0, stream>>>(nodesbf, Wkbf, nullptr, nullptr, nullptr, nullptr, Kbf,
                                               M2, 512, 512, 512, 512, 512, 1.0f, 1, 0, 0, 0, 0, 1, 0);
  gemm_n64<<<dim3(8, 33, 1), 256, 0, stream>>>(nodesbf, Wvbf, nullptr, nullptr, nullptr, nullptr, Vt,
                                               M2, 512, 512, 512, 512, MPAD, 1.0f, 2, 0, 0, 0, 0, 1, 0);

  if (use_s) {
    // --- S planes: S[h][n][m] = 0.125 * q_h(n) . k_h(m)  (batched over h) ---
    gemm_bf16<<<dim3(33, 32, 8), 256, 0, stream>>>(Qbf, Kbf, nullptr, nullptr, nullptr, nullptr, Splane,
                                                   4096, M2, 64, 512, 512, MPAD, 0.125f, 1,
                                                   64, 64, (size_t)4096 * MPAD, 0, 1, 0);
    // --- select + exp + raw_scores + attn_mean (block per n, LDS key cache) ---
    select_softmax<<<4096, 512, SSMEM, stream>>>(Splane, Zg, outA, outR);
    // --- PV (128x64 tiles, K-split x2, fp32 atomic accumulate) ---
    hipMemsetAsync(aopf, 0, 8388608, stream);
    gemm_n64<<<dim3(1, 32, 16), 256, 0, stream>>>(Splane, Vt, nullptr, nullptr, Zg, aopf, nullptr,
                                                  4096, 64, 2112, MPAD, MPAD, 512, 1.0f, 3,
                                                  (size_t)4096 * MPAD, (size_t)64 * MPAD, 64, 4096, 2, 2112);
    conv_bf<<<2048, 256, 0, stream>>>(aopf, aobf, 524288);
  } else {
    // fallback: raw_scores GEMM + fused attention
    gemm_bf16<<<dim3(33, 32, 1), 256, 0, stream>>>(Qbf, Kbf, nullptr, nullptr, nullptr, outR, nullptr,
                                                   4096, M2, 512, 512, 512, M2, 0.015625f, 0, 0, 0, 0, 0, 1, 0);
    fused_attn<<<256, 1024, SMEMSZ, stream>>>(Qbf, Kbf, Vt, aobf, outA);
  }

  // --- output projection + gate + final (128x64 tiles) ---
  gemm_n64<<<dim3(8, 32, 1), 256, 0, stream>>>(aobf, Wobf, bo, nullptr, nullptr, pj, nullptr,
                                               4096, 512, 512, 512, 512, 512, 1.0f, 0, 0, 0, 0, 0, 1, 0);
  cat_bf<<<4096, 256, 0, stream>>>(sfbf, pj, catbf);
  gemm_n64<<<dim3(8, 32, 1), 256, 0, stream>>>(catbf, Wagbf, bag, nullptr, nullptr, gl, nullptr,
                                               4096, 512, 1024, 1024, 1024, 512, 1.0f, 0, 0, 0, 0, 0, 1, 0);
  final_kernel<<<4096, 256, 0, stream>>>(sf, pj, gl, nw, outF, gpart);
  gate_reduce<<<1, 256, 0, stream>>>(gpart, outG);
}

// Round 22
// 784.836 us; speedup vs baseline: 1.1099x; 1.1099x over previous
//
#include <hip/hip_runtime.h>
#include <hip/hip_fp16.h>
#include <math.h>

// Problem constants
#define NS 4096      // N stocks
#define DIM 512      // D
#define NH 8         // heads
#define HD 64        // head dim
#define M2 4098      // N + 2 nodes
#define MPAD 4224    // m padded to multiple of 32
#define KKEEP 2048u  // top-k keep

// Output layout (floats): final_out | raw_scores | gate_mean | attn_mean
#define OUT_F 0
#define OUT_R 2097152          // 4096*512
#define OUT_G 18882560         // + 4096*4098
#define OUT_A 18882561

typedef __attribute__((ext_vector_type(8))) short bf16x8;
typedef __attribute__((ext_vector_type(4))) float f32x4;

__device__ __forceinline__ float sigmoidf_(float x) { return 1.0f / (1.0f + __expf(-x)); }

__device__ __forceinline__ unsigned short btrunc(float f) {   // f32 -> bf16 RNE
  unsigned u = __float_as_uint(f);
  u = u + 0x7FFFu + ((u >> 16) & 1u);
  return (unsigned short)(u >> 16);
}
__device__ __forceinline__ float bton(unsigned short h) {
  return __uint_as_float(((unsigned)h) << 16);
}

// wave suffix-scan over 256 bins (4/lane) and rank pick
__device__ __forceinline__ void scan_pick(unsigned c0, unsigned c1, unsigned c2, unsigned c3,
                                          unsigned k_rem, int lane,
                                          unsigned& bsel_out, unsigned& nxt_out) {
  unsigned run = c0 + c1 + c2 + c3;
  #pragma unroll
  for (int off = 1; off < 64; off <<= 1) {
    unsigned o_ = __shfl_down(run, off, 64);
    if (lane + off < 64) run += o_;
  }
  unsigned s0 = run, s1 = run - c0, s2 = s1 - c1, s3 = s2 - c2, s4 = s3 - c3;
  int which = -1;
  if      (s0 >= k_rem && s1 < k_rem) which = 0;
  else if (s1 >= k_rem && s2 < k_rem) which = 1;
  else if (s2 >= k_rem && s3 < k_rem) which = 2;
  else if (s3 >= k_rem && s4 < k_rem) which = 3;
  unsigned long long bal = __ballot(which >= 0);
  int src = (int)__ffsll(bal) - 1;
  unsigned nxtv = (which == 0) ? s1 : (which == 1) ? s2 : (which == 2) ? s3 : s4;
  unsigned bsel = (unsigned)(4 * lane + (which < 0 ? 0 : which));
  bsel_out = (unsigned)__shfl((int)bsel, src, 64);
  nxt_out  = (unsigned)__shfl((int)nxtv, src, 64);
}

// ---------------- regime_mod = sigmoid([zp,zs] @ Wg.T + bg) ----------------
__global__ __launch_bounds__(256) void regime_kernel(
    const float* __restrict__ zp, const float* __restrict__ zs,
    const float* __restrict__ Wg, const float* __restrict__ bg,
    float* __restrict__ regime) {
  __shared__ float zc[1024];
  int t = threadIdx.x;
  for (int i = t; i < 512; i += 256) { zc[i] = zp[i]; zc[512 + i] = zs[i]; }
  __syncthreads();
  for (int j = t; j < 512; j += 256) {
    const float4* w = (const float4*)(Wg + (size_t)j * 1024);
    float acc = 0.f;
    #pragma unroll 8
    for (int i = 0; i < 256; i++) {
      float4 wv = w[i];
      acc += wv.x * zc[4*i] + wv.y * zc[4*i+1] + wv.z * zc[4*i+2] + wv.w * zc[4*i+3];
    }
    regime[j] = sigmoidf_(acc + bg[j]);
  }
}

// ---------------- generic f32 -> bf16 convert ----------------
__global__ __launch_bounds__(256) void conv_bf(
    const float* __restrict__ src, unsigned short* __restrict__ dst, int n4) {
  int i4 = blockIdx.x * 256 + threadIdx.x;
  if (i4 >= n4) return;
  float4 v = *(const float4*)(src + (size_t)i4 * 4);
  ushort4 o; o.x = btrunc(v.x); o.y = btrunc(v.y); o.z = btrunc(v.z); o.w = btrunc(v.w);
  *(ushort4*)(dst + (size_t)i4 * 4) = o;
}

// ---------------- nodes = concat(zp, zs, sf) in bf16 ----------------
__global__ __launch_bounds__(256) void build_nodes_bf(
    const float* __restrict__ zp, const float* __restrict__ zs,
    const float* __restrict__ sf, unsigned short* __restrict__ nb) {
  int i4 = blockIdx.x * 256 + threadIdx.x;
  if (i4 >= (M2 * DIM) / 4) return;
  int idx = i4 * 4;
  int m = idx >> 9, c = idx & 511;
  const float* src = (m == 0) ? (zp + c) : (m == 1) ? (zs + c)
                               : (sf + (size_t)(m - 2) * 512 + c);
  float4 v = *(const float4*)src;
  ushort4 o; o.x = btrunc(v.x); o.y = btrunc(v.y); o.z = btrunc(v.z); o.w = btrunc(v.w);
  *(ushort4*)(nb + idx) = o;
}

// ---------------- bf16 MFMA GEMM 128x128 (z-batch + per-row scale) ----------------
#define LSTR 40
__global__ __launch_bounds__(256) void gemm_bf16(
    const unsigned short* __restrict__ A, const unsigned short* __restrict__ B,
    const float* __restrict__ bias, const float* __restrict__ cscale,
    const float* __restrict__ rscale,
    float* __restrict__ Cf, unsigned short* __restrict__ Cb,
    int M, int N, int K, int lda, int ldb, int ldc, float scale, int mode,
    size_t sA, size_t sB, size_t sC, size_t sR, int kz, int ksz) {
  __shared__ unsigned short As[128 * LSTR];
  __shared__ unsigned short Bs[128 * LSTR];
  const int z = blockIdx.z;
  const int zh = z / kz, zc = z - zh * kz;
  A += (size_t)zh * sA + (size_t)zc * ksz;
  B += (size_t)zh * sB + (size_t)zc * ksz;
  if (Cf) Cf += (size_t)zh * sC;
  if (Cb) Cb += (size_t)zh * sC;
  if (rscale) rscale += (size_t)zh * sR;
  const int t = threadIdx.x;
  const int w = t >> 6, lane = t & 63;
  const int wr = w >> 1, wc = w & 1;
  const int lr = lane & 15, lg = lane >> 4;
  const int bm = blockIdx.y * 128, bn = blockIdx.x * 128;
  f32x4 acc[4][4] = {};
  for (int k0 = 0; k0 < K; k0 += 32) {
    #pragma unroll
    for (int i = 0; i < 2; i++) {
      int q = t + i * 256;
      int row = q >> 2;
      int ko = (q & 3) * 8;
      bf16x8 av = {};
      int gr = bm + row;
      if (gr < M) av = *(const bf16x8*)(A + (size_t)gr * lda + k0 + ko);
      *(bf16x8*)(As + row * LSTR + ko) = av;
      bf16x8 bv = {};
      int gbr = bn + row;
      if (gbr < N) bv = *(const bf16x8*)(B + (size_t)gbr * ldb + k0 + ko);
      *(bf16x8*)(Bs + row * LSTR + ko) = bv;
    }
    __syncthreads();
    {
      bf16x8 af[4], bfr[4];
      #pragma unroll
      for (int i = 0; i < 4; i++)
        af[i] = *(const bf16x8*)(As + (64 * wr + 16 * i + lr) * LSTR + lg * 8);
      #pragma unroll
      for (int j = 0; j < 4; j++)
        bfr[j] = *(const bf16x8*)(Bs + (64 * wc + 16 * j + lr) * LSTR + lg * 8);
      #pragma unroll
      for (int i = 0; i < 4; i++)
        #pragma unroll
        for (int j = 0; j < 4; j++)
          acc[i][j] = __builtin_amdgcn_mfma_f32_16x16x32_bf16(af[i], bfr[j], acc[i][j], 0, 0, 0);
    }
    __syncthreads();
  }
  #pragma unroll
  for (int i = 0; i < 4; i++) {
    #pragma unroll
    for (int j = 0; j < 4; j++) {
      #pragma unroll
      for (int q = 0; q < 4; q++) {
        int row = bm + 64 * wr + 16 * i + lg * 4 + q;
        int col = bn + 64 * wc + 16 * j + lr;
        if (row < M && col < N) {
          float v = acc[i][j][q] * scale;
          if (bias)   v += bias[col];
          if (cscale) v *= cscale[col];
          if (rscale) v *= rscale[row];
          if (mode == 0)      Cf[(size_t)row * ldc + col] = v;
          else if (mode == 1) Cb[(size_t)row * ldc + col] = btrunc(v);
          else if (mode == 2) Cb[(size_t)col * ldc + row] = btrunc(v);
          else                atomicAdd(&Cf[(size_t)row * ldc + col], v);
        }
      }
    }
  }
}

// ---------------- bf16 MFMA GEMM 128x64 (full-occupancy variant) ----------------
__global__ __launch_bounds__(256) void gemm_n64(
    const unsigned short* __restrict__ A, const unsigned short* __restrict__ B,
    const float* __restrict__ bias, const float* __restrict__ cscale,
    const float* __restrict__ rscale,
    float* __restrict__ Cf, unsigned short* __restrict__ Cb,
    int M, int N, int K, int lda, int ldb, int ldc, float scale, int mode,
    size_t sA, size_t sB, size_t sC, size_t sR, int kz, int ksz) {
  __shared__ unsigned short As[128 * LSTR];
  __shared__ unsigned short Bs[64 * LSTR];
  const int z = blockIdx.z;
  const int zh = z / kz, zc = z - zh * kz;
  A += (size_t)zh * sA + (size_t)zc * ksz;
  B += (size_t)zh * sB + (size_t)zc * ksz;
  if (Cf) Cf += (size_t)zh * sC;
  if (Cb) Cb += (size_t)zh * sC;
  if (rscale) rscale += (size_t)zh * sR;
  const int t = threadIdx.x;
  const int w = t >> 6, lane = t & 63;
  const int lr = lane & 15, lg = lane >> 4;
  const int bm = blockIdx.y * 128, bn = blockIdx.x * 64;
  f32x4 acc[2][4] = {};
  for (int k0 = 0; k0 < K; k0 += 32) {
    {
      #pragma unroll
      for (int i = 0; i < 2; i++) {
        int q = t + i * 256;
        int row = q >> 2;
        int ko = (q & 3) * 8;
        bf16x8 av = {};
        int gr = bm + row;
        if (gr < M) av = *(const bf16x8*)(A + (size_t)gr * lda + k0 + ko);
        *(bf16x8*)(As + row * LSTR + ko) = av;
      }
      int row = t >> 2;
      int ko = (t & 3) * 8;
      bf16x8 bv = {};
      int gbr = bn + row;
      if (gbr < N) bv = *(const bf16x8*)(B + (size_t)gbr * ldb + k0 + ko);
      *(bf16x8*)(Bs + row * LSTR + ko) = bv;
    }
    __syncthreads();
    {
      bf16x8 af[2], bfr[4];
      #pragma unroll
      for (int i = 0; i < 2; i++)
        af[i] = *(const bf16x8*)(As + (32 * w + 16 * i + lr) * LSTR + lg * 8);
      #pragma unroll
      for (int j = 0; j < 4; j++)
        bfr[j] = *(const bf16x8*)(Bs + (16 * j + lr) * LSTR + lg * 8);
      #pragma unroll
      for (int i = 0; i < 2; i++)
        #pragma unroll
        for (int j = 0; j < 4; j++)
          acc[i][j] = __builtin_amdgcn_mfma_f32_16x16x32_bf16(af[i], bfr[j], acc[i][j], 0, 0, 0);
    }
    __syncthreads();
  }
  #pragma unroll
  for (int i = 0; i < 2; i++) {
    #pragma unroll
    for (int j = 0; j < 4; j++) {
      #pragma unroll
      for (int q = 0; q < 4; q++) {
        int row = bm + 32 * w + 16 * i + lg * 4 + q;
        int col = bn + 16 * j + lr;
        if (row < M && col < N) {
          float v = acc[i][j][q] * scale;
          if (bias)   v += bias[col];
          if (cscale) v *= cscale[col];
          if (rscale) v *= rscale[row];
          if (mode == 0)      Cf[(size_t)row * ldc + col] = v;
          else if (mode == 1) Cb[(size_t)row * ldc + col] = btrunc(v);
          else if (mode == 2) Cb[(size_t)col * ldc + row] = btrunc(v);
          else                atomicAdd(&Cf[(size_t)row * ldc + col], v);
        }
      }
    }
  }
}

// ---------------- select + exp + raw_scores + attn_mean (block per n, 8 waves = 8 heads) ----------------
// v4 = r17 LDS key cache (one global read) + fused raw_scores from cached keys.
#define SSMEM (8 * MPAD * 2 + 8 * 256 * 4 + 32 + 32)   // 75840 -> 2 blocks/CU
__global__ __launch_bounds__(512) void select_softmax(
    unsigned short* __restrict__ S, float* __restrict__ Zg,
    float* __restrict__ outA, float* __restrict__ outR) {
  extern __shared__ char sm[];
  unsigned short* keys = (unsigned short*)sm;              // [8][MPAD]
  unsigned* hist = (unsigned*)(sm + 8 * MPAD * 2);         // [8][256]
  float* Zs = (float*)(sm + 8 * MPAD * 2 + 8 * 256 * 4);   // [8]
  unsigned short* anchk = (unsigned short*)(sm + 8 * MPAD * 2 + 8 * 256 * 4 + 32); // [8][2]
  const int w = threadIdx.x >> 6, lane = threadIdx.x & 63;
  const int n = blockIdx.x;
  const size_t row = (size_t)w * 4096 + n;                 // head = w
  unsigned short* kr = keys + w * MPAD;
  unsigned* hw = hist + w * 256;
  unsigned short* g = S + row * MPAD;
  unsigned a0k = 0, a1k = 0;

  // s1: global read -> keys -> LDS + hi-byte hist + max (fused)
  hw[lane] = 0u; hw[lane + 64] = 0u; hw[lane + 128] = 0u; hw[lane + 192] = 0u;
  unsigned maxkey = 0;
  #pragma unroll
  for (int c = 0; c < 9; ++c) {
    if (c < 8 || lane < 16) {
      uint4 v = *(const uint4*)(g + c * 512 + lane * 8);
      unsigned* pv = (unsigned*)&v;
      int mb = c * 512 + lane * 8;
      #pragma unroll
      for (int p2 = 0; p2 < 4; ++p2) {
        unsigned pk = pv[p2], outw = 0;
        #pragma unroll
        for (int e = 0; e < 2; ++e) {
          int m = mb + 2 * p2 + e;
          unsigned u = (e == 0) ? (pk & 0xFFFFu) : (pk >> 16);
          unsigned key = u ^ ((u & 0x8000u) ? 0xFFFFu : 0x8000u);
          if (m < 2) { if (m == 0) a0k = key; else a1k = key; key = 0u; }
          else if (m >= M2) key = 0u;
          outw |= key << (16 * e);
          atomicAdd(&hw[key >> 8], 1u);
          if (key > maxkey) maxkey = key;
        }
        *(unsigned*)(kr + mb + 2 * p2) = outw;
      }
    }
  }
  if (lane == 0) { anchk[w * 2] = (unsigned short)a0k; anchk[w * 2 + 1] = (unsigned short)a1k; }
  if (a0k > maxkey) maxkey = a0k;   // nonzero only on lane 0
  if (a1k > maxkey) maxkey = a1k;
  #pragma unroll
  for (int off = 32; off > 0; off >>= 1) {
    unsigned o_ = (unsigned)__shfl_xor((int)maxkey, off, 64);
    if (o_ > maxkey) maxkey = o_;
  }
  float lmax = bton((unsigned short)(maxkey ^ ((maxkey & 0x8000u) ? 0x8000u : 0xFFFFu)));

  unsigned tb, k_rem = KKEEP;
  {
    unsigned c0 = hw[4*lane], c1 = hw[4*lane+1], c2 = hw[4*lane+2], c3 = hw[4*lane+3];
    unsigned nxtv;
    scan_pick(c0, c1, c2, c3, k_rem, lane, tb, nxtv);
    k_rem -= nxtv;
  }

  // s2: boundary-bin low-byte histogram (LDS keys)
  hw[lane] = 0u; hw[lane + 64] = 0u; hw[lane + 128] = 0u; hw[lane + 192] = 0u;
  #pragma unroll
  for (int c = 0; c < 9; ++c) {
    if (c < 8 || lane < 16) {
      uint4 v = *(const uint4*)(kr + c * 512 + lane * 8);
      const unsigned* pv = (const unsigned*)&v;
      #pragma unroll
      for (int p2 = 0; p2 < 4; ++p2) {
        unsigned lo = pv[p2] & 0xFFFFu, hi = pv[p2] >> 16;
        if ((lo >> 8) == tb) atomicAdd(&hw[lo & 255u], 1u);
        if ((hi >> 8) == tb) atomicAdd(&hw[hi & 255u], 1u);
      }
    }
  }
  unsigned thrkey;
  {
    unsigned c0 = hw[4*lane], c1 = hw[4*lane+1], c2 = hw[4*lane+2], c3 = hw[4*lane+3];
    unsigned bsel, nxtv;
    scan_pick(c0, c1, c2, c3, k_rem, lane, bsel, nxtv);
    thrkey = (tb << 8) | bsel;
  }
  __syncthreads();   // all waves' keys + anchk staged

  // raw pass: reconstruct S from keys (all heads) -> outR
  for (int m = threadIdx.x; m < M2; m += 512) {
    float s = 0.f;
    #pragma unroll
    for (int h = 0; h < 8; ++h) {
      unsigned key = (m < 2) ? (unsigned)anchk[h * 2 + m] : (unsigned)keys[h * MPAD + m];
      unsigned short us = (unsigned short)(key ^ ((key & 0x8000u) ? 0x8000u : 0xFFFFu));
      s += bton(us);
    }
    outR[(size_t)n * M2 + m] = s * 0.125f;
  }
  __syncthreads();   // raw reads done before e overwrite

  // s3: exp -> unnormalized e (bf16) to LDS + global; lsum of rounded e
  float lsum = 0.f;
  #pragma unroll
  for (int c = 0; c < 9; ++c) {
    if (c < 8 || lane < 16) {
      uint4 v = *(const uint4*)(kr + c * 512 + lane * 8);
      unsigned* pv = (unsigned*)&v;
      #pragma unroll
      for (int p2 = 0; p2 < 4; ++p2) {
        unsigned pk = pv[p2], outw = 0;
        bool anc = (c == 0 && lane == 0 && p2 == 0);
        if (anc) pk = a0k | (a1k << 16);
        #pragma unroll
        for (int e = 0; e < 2; ++e) {
          unsigned key = (e == 0) ? (pk & 0xFFFFu) : (pk >> 16);
          bool kept = anc || (key >= thrkey);
          unsigned short us = (unsigned short)(key ^ ((key & 0x8000u) ? 0x8000u : 0xFFFFu));
          float ev = kept ? __expf(bton(us) - lmax) : 0.f;
          unsigned short eb = btrunc(ev);
          lsum += bton(eb);
          outw |= ((unsigned)eb) << (16 * e);
        }
        pv[p2] = outw;
      }
      *(uint4*)(kr + c * 512 + lane * 8) = v;   // e into LDS for attn_mean
      *(uint4*)(g + c * 512 + lane * 8) = v;    // e to global for PV
    }
  }
  #pragma unroll
  for (int off = 32; off > 0; off >>= 1) lsum += __shfl_xor(lsum, off, 64);
  float invZ = 1.0f / lsum;
  if (lane == 0) { Zg[row] = invZ; Zs[w] = invZ; }
  __syncthreads();   // e + Zs visible to whole block

  // am pass: attn_mean[n][m] = (1/8) sum_h e[h][m] * invZ[h]
  for (int m = threadIdx.x; m < M2; m += 512) {
    float s = 0.f;
    #pragma unroll
    for (int h = 0; h < 8; ++h)
      s += bton(keys[h * MPAD + m]) * Zs[h];
    outA[(size_t)n * M2 + m] = s * 0.125f;
  }
}

// ================= FALLBACK PATH (round-14 fused kernel) =================
#define SROWB 8464
#define QOFF  (16 * SROWB)
#define HOFF  (QOFF + 16 * 72 * 2)
#define AOFF  (HOFF + 16 * 256 * 4)
#define SMEMSZ (AOFF + 64)

__global__ __launch_bounds__(1024) void fused_attn(
    const unsigned short* __restrict__ Qbf, const unsigned short* __restrict__ Kbf,
    const unsigned short* __restrict__ Vt, unsigned short* __restrict__ aobf,
    float* __restrict__ attn_mean_out) {
  extern __shared__ char dsm[];
  unsigned short* qt = (unsigned short*)(dsm + QOFF);
  unsigned* hist = (unsigned*)(dsm + HOFF);
  unsigned short* anchk = (unsigned short*)(dsm + AOFF);
  const int n0 = blockIdx.x * 16;
  const int t = threadIdx.x;
  const int w = t >> 6, lane = t & 63;
  const int lr = lane & 15, lg = lane >> 4;
  unsigned* hw = hist + w * 256;
  const int r = w;
  const unsigned swz = (unsigned)((r & 7) << 4);

  for (int h = 0; h < NH; ++h) {
    qt[(t >> 6) * 72 + (t & 63)] = Qbf[(size_t)(n0 + (t >> 6)) * DIM + h * HD + (t & 63)];
    __syncthreads();
    {
      bf16x8 a0 = *(const bf16x8*)(qt + lr * 72 + lg * 8);
      bf16x8 a1 = *(const bf16x8*)(qt + lr * 72 + 32 + lg * 8);
      #pragma unroll
      for (int f = 0; f < 17; ++f) {
        if (f < 16 || w < 8) {
          int m0 = (w + 16 * f) * 16;
          const unsigned short* kp = Kbf + (size_t)(m0 + lr) * DIM + h * HD + lg * 8;
          bf16x8 b0 = *(const bf16x8*)(kp);
          bf16x8 b1 = *(const bf16x8*)(kp + 32);
          f32x4 c = {0.f, 0.f, 0.f, 0.f};
          c = __builtin_amdgcn_mfma_f32_16x16x32_bf16(a0, b0, c, 0, 0, 0);
          c = __builtin_amdgcn_mfma_f32_16x16x32_bf16(a1, b1, c, 0, 0, 0);
          int m = m0 + lr;
          #pragma unroll
          for (int q = 0; q < 4; ++q) {
            int rr = lg * 4 + q;
            unsigned short us = btrunc(c[q] * 0.125f);
            unsigned key = (unsigned)us ^ ((us & 0x8000u) ? 0xFFFFu : 0x8000u);
            unsigned short stor = (m >= M2 || m < 2) ? (unsigned short)0 : (unsigned short)key;
            *(unsigned short*)(dsm + rr * SROWB + ((2 * m) ^ ((rr & 7) << 4))) = stor;
            if (m < 2) anchk[rr * 2 + m] = (unsigned short)key;
          }
        }
      }
    }
    __syncthreads();

    float invZ;
    {
      unsigned maxkey = 0;
      hw[lane] = 0u; hw[lane + 64] = 0u; hw[lane + 128] = 0u; hw[lane + 192] = 0u;
      #pragma unroll
      for (int c = 0; c < 9; ++c) {
        if (c < 8 || lane < 16) {
          uint4 pk4 = *(const uint4*)(dsm + r * SROWB + (((unsigned)(c * 1024 + lane * 16)) ^ swz));
          const unsigned* pw = (const unsigned*)&pk4;
          #pragma unroll
          for (int p2 = 0; p2 < 4; ++p2) {
            unsigned pk = pw[p2];
            unsigned lo = pk & 0xFFFFu, hi = pk >> 16;
            atomicAdd(&hw[lo >> 8], 1u);
            atomicAdd(&hw[hi >> 8], 1u);
            if (lo > maxkey) maxkey = lo;
            if (hi > maxkey) maxkey = hi;
          }
        }
      }
      #pragma unroll
      for (int off = 32; off > 0; off >>= 1) {
        unsigned o_ = (unsigned)__shfl_xor((int)maxkey, off, 64);
        if (o_ > maxkey) maxkey = o_;
      }
      {
        unsigned a0 = anchk[2 * r], a1 = anchk[2 * r + 1];
        if (a0 > maxkey) maxkey = a0;
        if (a1 > maxkey) maxkey = a1;
      }
      float lmax = bton((unsigned short)(maxkey ^ ((maxkey & 0x8000u) ? 0x8000u : 0xFFFFu)));

      unsigned tb, k_rem = KKEEP;
      {
        unsigned c0 = hw[4*lane], c1 = hw[4*lane+1], c2 = hw[4*lane+2], c3 = hw[4*lane+3];
        unsigned nxtv;
        scan_pick(c0, c1, c2, c3, k_rem, lane, tb, nxtv);
        k_rem -= nxtv;
      }
      hw[lane] = 0u; hw[lane + 64] = 0u; hw[lane + 128] = 0u; hw[lane + 192] = 0u;
      #pragma unroll
      for (int c = 0; c < 9; ++c) {
        if (c < 8 || lane < 16) {
          uint4 pk4 = *(const uint4*)(dsm + r * SROWB + (((unsigned)(c * 1024 + lane * 16)) ^ swz));
          const unsigned* pw = (const unsigned*)&pk4;
          #pragma unroll
          for (int p2 = 0; p2 < 4; ++p2) {
            unsigned pk = pw[p2];
            unsigned lo = pk & 0xFFFFu, hi = pk >> 16;
            if ((lo >> 8) == tb) atomicAdd(&hw[lo & 255u], 1u);
            if ((hi >> 8) == tb) atomicAdd(&hw[hi & 255u], 1u);
          }
        }
      }
      unsigned thrkey;
      {
        unsigned c0 = hw[4*lane], c1 = hw[4*lane+1], c2 = hw[4*lane+2], c3 = hw[4*lane+3];
        unsigned bsel, nxtv;
        scan_pick(c0, c1, c2, c3, k_rem, lane, bsel, nxtv);
        thrkey = (tb << 8) | bsel;
      }

      float lsum = 0.f;
      #pragma unroll
      for (int c = 0; c < 9; ++c) {
        if (c < 8 || lane < 16) {
          char* ap = dsm + r * SROWB + (((unsigned)(c * 1024 + lane * 16)) ^ swz);
          uint4 pk4 = *(const uint4*)ap;
          unsigned* pw = (unsigned*)&pk4;
          #pragma unroll
          for (int p2 = 0; p2 < 4; ++p2) {
            unsigned pk = pw[p2];
            bool anc = (c == 0 && lane == 0 && p2 == 0);
            if (anc) pk = (unsigned)anchk[2 * r] | ((unsigned)anchk[2 * r + 1] << 16);
            unsigned outw = 0;
            #pragma unroll
            for (int e = 0; e < 2; ++e) {
              unsigned key = (e == 0) ? (pk & 0xFFFFu) : (pk >> 16);
              bool kept = anc || (key >= thrkey);
              unsigned short us = (unsigned short)(key ^ ((key & 0x8000u) ? 0x8000u : 0xFFFFu));
              float evf = kept ? __expf(bton(us) - lmax) : 0.f;
              unsigned short eb = btrunc(evf);
              lsum += bton(eb);
              outw |= ((unsigned)eb) << (16 * e);
            }
            pw[p2] = outw;
          }
          *(uint4*)ap = pk4;
        }
      }
      #pragma unroll
      for (int off = 32; off > 0; off >>= 1) lsum += __shfl_xor(lsum, off, 64);
      invZ = 1.0f / lsum;
      for (int c = 0; c < 9; ++c) {
        if (c < 8 || lane < 16) {
          const char* ap = dsm + r * SROWB + (((unsigned)(c * 1024 + lane * 16)) ^ swz);
          uint4 e4 = *(const uint4*)ap;
          const unsigned* pw = (const unsigned*)&e4;
          int bm = c * 512 + lane * 8;
          float* base = attn_mean_out + (size_t)(n0 + r) * M2 + bm;
          #pragma unroll
          for (int p2 = 0; p2 < 4; ++p2) {
            float v0 = bton((unsigned short)(pw[p2] & 0xFFFFu)) * invZ * 0.125f;
            float v1 = bton((unsigned short)(pw[p2] >> 16)) * invZ * 0.125f;
            int m = bm + 2 * p2;
            if (m < M2)     { if (h == 0) base[2*p2] = v0;   else base[2*p2] += v0; }
            if (m + 1 < M2) { if (h == 0) base[2*p2+1] = v1; else base[2*p2+1] += v1; }
          }
        }
      }
    }
    __syncthreads();

    {
      f32x4 o0 = {0.f,0.f,0.f,0.f}, o1 = o0, o2 = o0, o3 = o0;
      const unsigned short* Vb = Vt + (size_t)(h * HD) * MPAD;
      #pragma unroll
      for (int ks = 0; ks < 9; ++ks) {
        if (ks < 8 || w < 4) {
          int kk = (w + 16 * ks) * 32 + lg * 8;
          bf16x8 a = *(const bf16x8*)(dsm + lr * SROWB + ((2 * kk) ^ ((lr & 7) << 4)));
          {
            bf16x8 b0 = *(const bf16x8*)(Vb + (size_t)(lr) * MPAD + kk);
            bf16x8 b1 = *(const bf16x8*)(Vb + (size_t)(16 + lr) * MPAD + kk);
            o0 = __builtin_amdgcn_mfma_f32_16x16x32_bf16(a, b0, o0, 0, 0, 0);
            o1 = __builtin_amdgcn_mfma_f32_16x16x32_bf16(a, b1, o1, 0, 0, 0);
          }
          {
            bf16x8 b2 = *(const bf16x8*)(Vb + (size_t)(32 + lr) * MPAD + kk);
            bf16x8 b3 = *(const bf16x8*)(Vb + (size_t)(48 + lr) * MPAD + kk);
            o2 = __builtin_amdgcn_mfma_f32_16x16x32_bf16(a, b2, o2, 0, 0, 0);
            o3 = __builtin_amdgcn_mfma_f32_16x16x32_bf16(a, b3, o3, 0, 0, 0);
          }
        }
      }
      __syncthreads();
      float* part = (float*)dsm;
      #pragma unroll
      for (int q = 0; q < 4; q++) {
        int row = lg * 4 + q;
        part[w * 1024 + row * 64 +      lr] = o0[q];
        part[w * 1024 + row * 64 + 16 + lr] = o1[q];
        part[w * 1024 + row * 64 + 32 + lr] = o2[q];
        part[w * 1024 + row * 64 + 48 + lr] = o3[q];
      }
      __syncthreads();
      {
        float s = 0.f;
        #pragma unroll
        for (int ww = 0; ww < 16; ++ww) s += part[ww * 1024 + t];
        aobf[(size_t)(n0 + (t >> 6)) * DIM + h * HD + (t & 63)] = btrunc(s * invZ);
      }
    }
  }
}

// ---------------- concat(sfbf, bf16(pj)) ----------------
__global__ __launch_bounds__(256) void cat_bf(
    const unsigned short* __restrict__ sfbf, const float* __restrict__ pj,
    unsigned short* __restrict__ cat) {
  int i4 = blockIdx.x * 256 + threadIdx.x;
  if (i4 >= (4096 * 1024) / 4) return;
  int idx = i4 * 4;
  int n = idx >> 10, c = idx & 1023;
  if (c < 512) {
    *(ushort4*)(cat + idx) = *(const ushort4*)(sfbf + (size_t)n * 512 + c);
  } else {
    float4 v = *(const float4*)(pj + (size_t)n * 512 + (c - 512));
    ushort4 o; o.x = btrunc(v.x); o.y = btrunc(v.y); o.z = btrunc(v.z); o.w = btrunc(v.w);
    *(ushort4*)(cat + idx) = o;
  }
}

// ---------------- gate, residual, RMSNorm, gate partial sums ----------------
__global__ __launch_bounds__(256) void final_kernel(
    const float* __restrict__ sf, const float* __restrict__ pj,
    const float* __restrict__ gl, const float* __restrict__ norm_w,
    float* __restrict__ outf, float* __restrict__ gpart) {
  int n = blockIdx.x, t = threadIdx.x;
  __shared__ float red[256];
  size_t base = (size_t)n * 512;
  float g0 = sigmoidf_(gl[base + t]);
  float g1 = sigmoidf_(gl[base + 256 + t]);
  float x0 = sf[base + t], x1 = sf[base + 256 + t];
  float p0 = pj[base + t], p1 = pj[base + 256 + t];
  float gr0 = x0 + g0 * p0, gr1 = x1 + g1 * p1;

  red[t] = g0 + g1;
  __syncthreads();
  for (int off = 128; off > 0; off >>= 1) {
    if (t < off) red[t] += red[t + off];
    __syncthreads();
  }
  if (t == 0) gpart[n] = red[0];
  __syncthreads();

  red[t] = gr0 * gr0 + gr1 * gr1;
  __syncthreads();
  for (int off = 128; off > 0; off >>= 1) {
    if (t < off) red[t] += red[t + off];
    __syncthreads();
  }
  float rms = rsqrtf(red[0] * (1.0f / 512.0f) + 1e-6f);
  outf[base + t] = gr0 * rms * norm_w[t];
  outf[base + 256 + t] = gr1 * rms * norm_w[256 + t];
}

__global__ __launch_bounds__(256) void gate_reduce(
    const float* __restrict__ gpart, float* __restrict__ out_scalar) {
  __shared__ float red[256];
  int t = threadIdx.x;
  float s = 0.f;
  for (int i = t; i < 4096; i += 256) s += gpart[i];
  red[t] = s;
  __syncthreads();
  for (int off = 128; off > 0; off >>= 1) {
    if (t < off) red[t] += red[t + off];
    __syncthreads();
  }
  if (t == 0) out_scalar[0] = red[0] * (1.0f / (4096.0f * 512.0f));
}

extern "C" void kernel_launch(void* const* d_in, const int* in_sizes, int n_in,
                              void* d_out, int out_size, void* d_ws, size_t ws_size,
                              hipStream_t stream) {
  const float* sf  = (const float*)d_in[0];
  const float* zp  = (const float*)d_in[1];
  const float* zs  = (const float*)d_in[2];
  const float* Wq  = (const float*)d_in[3];
  const float* Wk  = (const float*)d_in[4];
  const float* Wv  = (const float*)d_in[5];
  const float* Wg  = (const float*)d_in[6];
  const float* bg  = (const float*)d_in[7];
  const float* Wag = (const float*)d_in[8];
  const float* bag = (const float*)d_in[9];
  const float* nw  = (const float*)d_in[10];
  const float* Wo  = (const float*)d_in[11];
  const float* bo  = (const float*)d_in[12];

  float* out  = (float*)d_out;
  float* outF = out + OUT_F;
  float* outR = out + OUT_R;
  float* outG = out + OUT_G;
  float* outA = out + OUT_A;

  // workspace layout (bytes)
  char* W = (char*)d_ws;
  float*          regime  = (float*)(W + 0);                 // 2048
  float*          gpart   = (float*)(W + 2048);              // 16384
  unsigned short* sfbf    = (unsigned short*)(W + 18432);    // 4,194,304
  unsigned short* nodesbf = (unsigned short*)(W + 4212736);  // 4,196,352
  unsigned short* Qbf     = (unsigned short*)(W + 8409088);  // 4,194,304
  unsigned short* Kbf     = (unsigned short*)(W + 12603392); // 4,325,376
  unsigned short* Vt      = (unsigned short*)(W + 16928768); // 4,325,376 (512 x 4224)
  unsigned short* aobf    = (unsigned short*)(W + 21254144); // 4,194,304
  unsigned short* catbf   = (unsigned short*)(W + 25448448); // 8,388,608
  unsigned short* Wqbf    = (unsigned short*)(W + 33837056); // 524,288
  unsigned short* Wkbf    = (unsigned short*)(W + 34361344); // 524,288
  unsigned short* Wvbf    = (unsigned short*)(W + 34885632); // 524,288
  unsigned short* Wobf    = (unsigned short*)(W + 35409920); // 524,288
  unsigned short* Wagbf   = (unsigned short*)(W + 35934208); // 1,048,576
  float*          pj      = (float*)(W + 36982784);          // 8,388,608 -> 45,371,392
  float*          gl      = (float*)(W + 4212736);           // alias (dead by then)
  unsigned short* Splane  = (unsigned short*)(W + 45371392); // 276,824,064 -> 322,195,456
  float*          Zg      = (float*)(W + 322195456);         // 131,072 -> 322,326,528
  float*          aopf    = (float*)(W + 322326528);         // 8,388,608 -> 330,715,136
  const size_t need_s = 330715136ull;
  const int use_s = (ws_size >= need_s) ? 1 : 0;

  hipFuncSetAttribute((const void*)fused_attn,
                      hipFuncAttributeMaxDynamicSharedMemorySize, SMEMSZ);
  hipFuncSetAttribute((const void*)select_softmax,
                      hipFuncAttributeMaxDynamicSharedMemorySize, SSMEM);

  // --- small prep ---
  regime_kernel<<<1, 256, 0, stream>>>(zp, zs, Wg, bg, regime);
  conv_bf<<<2048, 256, 0, stream>>>(sf, sfbf, 524288);
  build_nodes_bf<<<2049, 256, 0, stream>>>(zp, zs, sf, nodesbf);
  conv_bf<<<256, 256, 0, stream>>>(Wq, Wqbf, 65536);
  conv_bf<<<256, 256, 0, stream>>>(Wk, Wkbf, 65536);
  conv_bf<<<256, 256, 0, stream>>>(Wv, Wvbf, 65536);
  conv_bf<<<256, 256, 0, stream>>>(Wo, Wobf, 65536);
  conv_bf<<<512, 256, 0, stream>>>(Wag, Wagbf, 131072);
  hipMemsetAsync(Kbf, 0, 4325376, stream);
  hipMemsetAsync(Vt, 0, 4325376, stream);

  // --- projections (bf16 MFMA, 128x64 tiles) ---
  gemm_n64<<<dim3(8, 32, 1), 256, 0, stream>>>(sfbf, Wqbf, nullptr, regime, nullptr, nullptr, Qbf,
                                               4096, 512, 512, 512, 512, 512, 1.0f, 1, 0, 0, 0, 0, 1, 0);
  gemm_n64<<<dim3(8, 33, 1), 256, 0, stream>>>(nodesbf, Wkbf, nullptr, nullptr, nullptr, nullptr, Kbf,
                                               M2, 512, 512, 512, 512, 512, 1.0f, 1, 0, 0, 0, 0, 1, 0);
  gemm_n64<<<dim3(8, 33, 1), 256, 0, stream>>>(nodesbf, Wvbf, nullptr, nullptr, nullptr, nullptr, Vt,
                                               M2, 512, 512, 512, 512, MPAD, 1.0f, 2, 0, 0, 0, 0, 1, 0);

  if (use_s) {
    // --- S planes: S[h][n][m] = 0.125 * q_h(n) . k_h(m)  (batched over h) ---
    gemm_bf16<<<dim3(33, 32, 8), 256, 0, stream>>>(Qbf, Kbf, nullptr, nullptr, nullptr, nullptr, Splane,
                                                   4096, M2, 64, 512, 512, MPAD, 0.125f, 1,
                                                   64, 64, (size_t)4096 * MPAD, 0, 1, 0);
    // --- select + exp + raw_scores + attn_mean (block per n, LDS key cache) ---
    select_softmax<<<4096, 512, SSMEM, stream>>>(Splane, Zg, outA, outR);
    // --- PV (128x64 tiles, K-split x2, fp32 atomic accumulate) ---
    hipMemsetAsync(aopf, 0, 8388608, stream);
    gemm_n64<<<dim3(1, 32, 16), 256, 0, stream>>>(Splane, Vt, nullptr, nullptr, Zg, aopf, nullptr,
                                                  4096, 64, 2112, MPAD, MPAD, 512, 1.0f, 3,
                                                  (size_t)4096 * MPAD, (size_t)64 * MPAD, 64, 4096, 2, 2112);
    conv_bf<<<2048, 256, 0, stream>>>(aopf, aobf, 524288);
  } else {
    // fallback: raw_scores GEMM + fused attention
    gemm_bf16<<<dim3(33, 32, 1), 256, 0, stream>>>(Qbf, Kbf, nullptr, nullptr, nullptr, outR, nullptr,
                                                   4096, M2, 512, 512, 512, M2, 0.015625f, 0, 0, 0, 0, 0, 1, 0);
    fused_attn<<<256, 1024, SMEMSZ, stream>>>(Qbf, Kbf, Vt, aobf, outA);
  }

  // --- output projection + gate + final (128x64 tiles) ---
  gemm_n64<<<dim3(8, 32, 1), 256, 0, stream>>>(aobf, Wobf, bo, nullptr, nullptr, pj, nullptr,
                                               4096, 512, 512, 512, 512, 512, 1.0f, 0, 0, 0, 0, 0, 1, 0);
  cat_bf<<<4096, 256, 0, stream>>>(sfbf, pj, catbf);
  gemm_n64<<<dim3(8, 32, 1), 256, 0, stream>>>(catbf, Wagbf, bag, nullptr, nullptr, gl, nullptr,
                                               4096, 512, 1024, 1024, 1024, 512, 1.0f, 0, 0, 0, 0, 0, 1, 0);
  final_kernel<<<4096, 256, 0, stream>>>(sf, pj, gl, nw, outF, gpart);
  gate_reduce<<<1, 256, 0, stream>>>(gpart, outG);
}